// Round 1
// baseline (1897.427 us; speedup 1.0000x reference)
//
#include <hip/hip_runtime.h>

#define NCONES 8
#define NN 24
#define REGEPS 1e-7f
#define POWER_ITERS 30
#define FISTA_ITERS 200

// upper-triangle index for symmetric 24x24 (i<=j)
__device__ __host__ constexpr int tri(int i, int j) {
    return i * NN - i * (i - 1) / 2 + (j - i);
}

__global__ void __launch_bounds__(64, 1)
qcqp_kernel(const float* __restrict__ P, const float* __restrict__ qv,
            float* __restrict__ out, int Btot) {
    const int b = blockIdx.x * blockDim.x + threadIdx.x;
    if (b >= Btot) return;

    const float* __restrict__ Pb = P + (size_t)b * (NN * NN);
    const float* __restrict__ qb = qv + (size_t)b * NN;

    // ---- Phase 1: G = A^T A (symmetric, upper-tri), bb = -P^T q ----
    float G[300];
#pragma unroll
    for (int i = 0; i < 300; ++i) G[i] = 0.f;
    float bb[NN];
#pragma unroll
    for (int i = 0; i < NN; ++i) bb[i] = 0.f;

#pragma unroll 1
    for (int k = 0; k < NN; ++k) {
        float row[NN];
#pragma unroll
        for (int m = 0; m < NN / 4; ++m) {
            float4 v = *reinterpret_cast<const float4*>(Pb + k * NN + 4 * m);
            row[4 * m + 0] = v.x;
            row[4 * m + 1] = v.y;
            row[4 * m + 2] = v.z;
            row[4 * m + 3] = v.w;
        }
        const float qk = qb[k];  // scalar global load (L1-hot), avoids runtime-indexed local array
        float a[NN];
#pragma unroll
        for (int i = 0; i < NN; ++i) {
            bb[i] -= row[i] * qk;                    // b = -P^T q (uses P, not A)
            a[i] = row[i] + ((i == k) ? REGEPS : 0.f);  // A = P + REG*I
        }
#pragma unroll
        for (int i = 0; i < NN; ++i)
#pragma unroll
            for (int j = i; j < NN; ++j)
                G[tri(i, j)] += a[i] * a[j];
    }

    // ---- Phase 2: power iteration for step = 1/(L + 1e-12) ----
    float v[NN];
    {
        const float iv = 0.20412414523193150818f;  // 1/sqrt(24)
#pragma unroll
        for (int i = 0; i < NN; ++i) v[i] = iv;
    }

#pragma unroll 1
    for (int it = 0; it < POWER_ITERS; ++it) {
        float w[NN];
#pragma unroll
        for (int i = 0; i < NN; ++i) w[i] = 0.f;
#pragma unroll
        for (int i = 0; i < NN; ++i) {
#pragma unroll
            for (int j = 0; j < NN; ++j) {
                const int lo = (i < j) ? i : j;
                const int hi = (i < j) ? j : i;
                w[i] += G[tri(lo, hi)] * v[j];
            }
        }
        float nrm = 0.f;
#pragma unroll
        for (int i = 0; i < NN; ++i) nrm += w[i] * w[i];
        const float inv = 1.f / (sqrtf(nrm) + 1e-30f);
#pragma unroll
        for (int i = 0; i < NN; ++i) v[i] = w[i] * inv;
    }
    // L = v^T G v
    float L = 0.f;
    {
#pragma unroll
        for (int i = 0; i < NN; ++i) {
            float wi = 0.f;
#pragma unroll
            for (int j = 0; j < NN; ++j) {
                const int lo = (i < j) ? i : j;
                const int hi = (i < j) ? j : i;
                wi += G[tri(lo, hi)] * v[j];
            }
            L += v[i] * wi;
        }
    }
    const float step = 1.f / (L + 1e-12f);

    // ---- Phase 3: FISTA ----
    float l[NN], y[NN];
#pragma unroll
    for (int i = 0; i < NN; ++i) { l[i] = 0.f; y[i] = 0.f; }
    float tk = 1.f;

#pragma unroll 1
    for (int it = 0; it < FISTA_ITERS; ++it) {
        // grad = G y + bb ; z = y - step*grad
        float z[NN];
#pragma unroll
        for (int i = 0; i < NN; ++i) {
            float g = bb[i];
#pragma unroll
            for (int j = 0; j < NN; ++j) {
                const int lo = (i < j) ? i : j;
                const int hi = (i < j) ? j : i;
                g += G[tri(lo, hi)] * y[j];
            }
            z[i] = y[i] - step * g;
        }
        // SOC projection
        float ln[NN];
#pragma unroll
        for (int c = 0; c < NCONES; ++c) {
            const float t  = z[c];
            const float x1 = z[NCONES + 2 * c];
            const float x2 = z[NCONES + 2 * c + 1];
            const float nx = sqrtf(x1 * x1 + x2 * x2);
            const float alpha = 0.5f * (t + nx);
            const bool inside = (nx <= t);
            const bool zero_  = (nx <= -t);
            const float tout = inside ? t : (zero_ ? 0.f : alpha);
            const float sc   = inside ? 1.f : (zero_ ? 0.f : alpha / fmaxf(nx, 1e-12f));
            ln[c] = tout;
            ln[NCONES + 2 * c]     = x1 * sc;
            ln[NCONES + 2 * c + 1] = x2 * sc;
        }
        const float tk_new = 0.5f * (1.f + sqrtf(1.f + 4.f * tk * tk));
        const float bet = (tk - 1.f) / tk_new;
#pragma unroll
        for (int i = 0; i < NN; ++i) {
            y[i] = ln[i] + bet * (ln[i] - l[i]);
            l[i] = ln[i];
        }
        tk = tk_new;
    }

    // ---- store ----
    float* __restrict__ ob = out + (size_t)b * NN;
#pragma unroll
    for (int m = 0; m < NN / 4; ++m) {
        float4 vv;
        vv.x = l[4 * m + 0];
        vv.y = l[4 * m + 1];
        vv.z = l[4 * m + 2];
        vv.w = l[4 * m + 3];
        *reinterpret_cast<float4*>(ob + 4 * m) = vv;
    }
}

extern "C" void kernel_launch(void* const* d_in, const int* in_sizes, int n_in,
                              void* d_out, int out_size, void* d_ws, size_t ws_size,
                              hipStream_t stream) {
    const float* P = (const float*)d_in[0];
    const float* q = (const float*)d_in[1];
    float* out = (float*)d_out;
    const int Btot = in_sizes[0] / (NN * NN);
    const int block = 64;
    const int grid = (Btot + block - 1) / block;
    qcqp_kernel<<<grid, block, 0, stream>>>(P, q, out, Btot);
}

// Round 2
// 259.007 us; speedup vs baseline: 7.3258x; 7.3258x over previous
//
#include <hip/hip_runtime.h>

#define NN 24
#define POWER_ITERS 30
#define FISTA_ITERS 200

// Group-of-4-lane broadcast: every lane reads the value held by lane (groupbase|ML).
// ds_swizzle BitMode: src = (lane & and_mask) | or_mask ; and=0x1C keeps the 4-group base.
template<int ML>
__device__ __forceinline__ float grp_bcast(float v) {
    return __int_as_float(__builtin_amdgcn_ds_swizzle(__float_as_int(v), (ML << 5) | 0x1C));
}
__device__ __forceinline__ float grp_xor1(float v) {
    return __int_as_float(__builtin_amdgcn_ds_swizzle(__float_as_int(v), 0x041F));
}
__device__ __forceinline__ float grp_xor2(float v) {
    return __int_as_float(__builtin_amdgcn_ds_swizzle(__float_as_int(v), 0x081F));
}

// Rebuild the full 24-vector (replicated in each lane) from each lane's 6 owned
// components. Ownership: lane ls owns global rows {2ls, 2ls+1, 8+4ls .. 11+4ls}
// stored at local idx {0,1,2,3,4,5}. All swizzle patterns/indices compile-time.
#define GATHER24(dst, s) do { \
    dst[0]=grp_bcast<0>(s[0]);  dst[1]=grp_bcast<0>(s[1]); \
    dst[2]=grp_bcast<1>(s[0]);  dst[3]=grp_bcast<1>(s[1]); \
    dst[4]=grp_bcast<2>(s[0]);  dst[5]=grp_bcast<2>(s[1]); \
    dst[6]=grp_bcast<3>(s[0]);  dst[7]=grp_bcast<3>(s[1]); \
    dst[8]=grp_bcast<0>(s[2]);  dst[9]=grp_bcast<0>(s[3]);  dst[10]=grp_bcast<0>(s[4]); dst[11]=grp_bcast<0>(s[5]); \
    dst[12]=grp_bcast<1>(s[2]); dst[13]=grp_bcast<1>(s[3]); dst[14]=grp_bcast<1>(s[4]); dst[15]=grp_bcast<1>(s[5]); \
    dst[16]=grp_bcast<2>(s[2]); dst[17]=grp_bcast<2>(s[3]); dst[18]=grp_bcast<2>(s[4]); dst[19]=grp_bcast<2>(s[5]); \
    dst[20]=grp_bcast<3>(s[2]); dst[21]=grp_bcast<3>(s[3]); dst[22]=grp_bcast<3>(s[4]); dst[23]=grp_bcast<3>(s[5]); \
} while (0)

__device__ __forceinline__ void proj_cone(float t, float x1, float x2,
                                          float& to, float& xo1, float& xo2) {
    const float nx = sqrtf(x1 * x1 + x2 * x2);
    const float alpha = 0.5f * (t + nx);
    const bool inside = (nx <= t);
    const bool zero_  = (nx <= -t);
    to = inside ? t : (zero_ ? 0.f : alpha);
    const float sc = inside ? 1.f : (zero_ ? 0.f : alpha / fmaxf(nx, 1e-12f));
    xo1 = x1 * sc;
    xo2 = x2 * sc;
}

__global__ void __launch_bounds__(256, 2)
qcqp_kernel(const float* __restrict__ P, const float* __restrict__ qv,
            float* __restrict__ out, int Btot) {
    const int tid = blockIdx.x * blockDim.x + threadIdx.x;
    const int b = tid >> 2;
    if (b >= Btot) return;
    const int ls = tid & 3;  // sub-lane in 4-lane group

    const float* __restrict__ Pb = P + (size_t)b * (NN * NN);
    const float* __restrict__ qb = qv + (size_t)b * NN;

    const int r01 = 2 * ls;      // global rows for local idx 0,1 (cone t's)
    const int r25 = 8 + 4 * ls;  // global rows for local idx 2..5 (cone x's)

    // ---- Phase 1: own 6 rows of G = A^T A (REG=1e-7 dropped: ~3e-8 relative
    // effect on G, far below the 0.12 threshold), bb = -(P^T q) own rows ----
    float G[6][NN];
    float bb[6];
#pragma unroll
    for (int il = 0; il < 6; ++il) {
        bb[il] = 0.f;
#pragma unroll
        for (int j = 0; j < NN; ++j) G[il][j] = 0.f;
    }

#pragma unroll 1
    for (int k = 0; k < NN; ++k) {
        const float* rp = Pb + k * NN;
        float row[NN];
#pragma unroll
        for (int m = 0; m < 6; ++m) {
            const float4 v4 = *reinterpret_cast<const float4*>(rp + 4 * m);
            row[4 * m + 0] = v4.x;
            row[4 * m + 1] = v4.y;
            row[4 * m + 2] = v4.z;
            row[4 * m + 3] = v4.w;
        }
        const float2 o01 = *reinterpret_cast<const float2*>(rp + r01);   // 8B aligned
        const float4 o25 = *reinterpret_cast<const float4*>(rp + r25);   // 16B aligned
        const float qk = qb[k];
        const float ao[6] = {o01.x, o01.y, o25.x, o25.y, o25.z, o25.w};
#pragma unroll
        for (int il = 0; il < 6; ++il) {
            bb[il] -= ao[il] * qk;
#pragma unroll
            for (int j = 0; j < NN; ++j) G[il][j] += ao[il] * row[j];
        }
    }

    // ---- Phase 2: power iteration -> step = 1/(L + 1e-12) ----
    float vf[NN];   // full v, replicated across the group
    float vo[6];    // own components
#pragma unroll
    for (int j = 0; j < NN; ++j) vf[j] = 0.20412414523193150818f;  // 1/sqrt(24)
#pragma unroll
    for (int il = 0; il < 6; ++il) vo[il] = 0.20412414523193150818f;

#pragma unroll 1
    for (int it = 0; it < POWER_ITERS; ++it) {
        float w[6];
#pragma unroll
        for (int il = 0; il < 6; ++il) {
            float acc = 0.f;
#pragma unroll
            for (int j = 0; j < NN; ++j) acc += G[il][j] * vf[j];
            w[il] = acc;
        }
        float n2 = w[0] * w[0];
#pragma unroll
        for (int il = 1; il < 6; ++il) n2 += w[il] * w[il];
        n2 += grp_xor1(n2);
        n2 += grp_xor2(n2);
        const float inv = 1.f / (sqrtf(n2) + 1e-30f);
#pragma unroll
        for (int il = 0; il < 6; ++il) vo[il] = w[il] * inv;
        GATHER24(vf, vo);
    }

    // L = v^T G v (group-reduced)
    float Lp = 0.f;
#pragma unroll
    for (int il = 0; il < 6; ++il) {
        float acc = 0.f;
#pragma unroll
        for (int j = 0; j < NN; ++j) acc += G[il][j] * vf[j];
        Lp += vo[il] * acc;
    }
    Lp += grp_xor1(Lp);
    Lp += grp_xor2(Lp);
    const float step = 1.f / (Lp + 1e-12f);

    // ---- Phase 3: FISTA ----
    float yf[NN];            // full y, replicated
    float yo[6], lo[6];      // own components of y and l
#pragma unroll
    for (int j = 0; j < NN; ++j) yf[j] = 0.f;
#pragma unroll
    for (int il = 0; il < 6; ++il) { yo[il] = 0.f; lo[il] = 0.f; }
    float tk = 1.f;

#pragma unroll 1
    for (int it = 0; it < FISTA_ITERS; ++it) {
        float z[6];
#pragma unroll
        for (int il = 0; il < 6; ++il) {
            float g = bb[il];
#pragma unroll
            for (int j = 0; j < NN; ++j) g += G[il][j] * yf[j];
            z[il] = yo[il] - step * g;
        }
        // Local SOC projection: local idx {0;2,3} = cone 2ls, {1;4,5} = cone 2ls+1
        float ln[6];
        proj_cone(z[0], z[2], z[3], ln[0], ln[2], ln[3]);
        proj_cone(z[1], z[4], z[5], ln[1], ln[4], ln[5]);
        const float tkn = 0.5f * (1.f + sqrtf(1.f + 4.f * tk * tk));
        const float bet = (tk - 1.f) / tkn;
        tk = tkn;
        float yn[6];
#pragma unroll
        for (int il = 0; il < 6; ++il) {
            yn[il] = ln[il] + bet * (ln[il] - lo[il]);
            lo[il] = ln[il];
            yo[il] = yn[il];
        }
        GATHER24(yf, yn);
    }

    // ---- store own components (disjoint across the group, covers all 24) ----
    float* ob = out + (size_t)b * NN;
    *reinterpret_cast<float2*>(ob + r01) = make_float2(lo[0], lo[1]);
    *reinterpret_cast<float4*>(ob + r25) = make_float4(lo[2], lo[3], lo[4], lo[5]);
}

extern "C" void kernel_launch(void* const* d_in, const int* in_sizes, int n_in,
                              void* d_out, int out_size, void* d_ws, size_t ws_size,
                              hipStream_t stream) {
    const float* P = (const float*)d_in[0];
    const float* q = (const float*)d_in[1];
    float* out = (float*)d_out;
    const int Btot = in_sizes[0] / (NN * NN);
    const int threads = 4 * Btot;
    const int block = 256;
    const int grid = (threads + block - 1) / block;
    qcqp_kernel<<<grid, block, 0, stream>>>(P, q, out, Btot);
}

// Round 3
// 197.160 us; speedup vs baseline: 9.6238x; 1.3137x over previous
//
#include <hip/hip_runtime.h>

#define NN 24
#define POWER_ITERS 30
#define FISTA_ITERS 200

// 8-lane-group broadcast: every lane reads the value held by lane (group_base | ML).
// ds_swizzle BitMode: src_lane = ((lane & and) | or) ^ xor ; and=0x18 keeps 8-group base.
template<int ML>
__device__ __forceinline__ float bc8(float v) {
    return __int_as_float(__builtin_amdgcn_ds_swizzle(__float_as_int(v), (ML << 5) | 0x18));
}
__device__ __forceinline__ float gx1(float v) {
    return __int_as_float(__builtin_amdgcn_ds_swizzle(__float_as_int(v), 0x041F));
}
__device__ __forceinline__ float gx2(float v) {
    return __int_as_float(__builtin_amdgcn_ds_swizzle(__float_as_int(v), 0x081F));
}
__device__ __forceinline__ float gx4(float v) {
    return __int_as_float(__builtin_amdgcn_ds_swizzle(__float_as_int(v), 0x101F));
}

// Fused gather+matvec: g0..g2 += G * full_vec, where full_vec is distributed
// across the 8-lane group as (s0 -> row ls ; s1,s2 -> rows 8+2ls, 9+2ls).
// Element j of the full vector: j in [0,8): lane j slot0; j = 8+2c+e: lane c slot 1+e.
#define MV(j, bexpr) { const float vj = (bexpr); \
    g0 = fmaf(Gm[0][j], vj, g0); g1 = fmaf(Gm[1][j], vj, g1); g2 = fmaf(Gm[2][j], vj, g2); }
#define MATVEC(s0, s1, s2) do { \
    MV(0,  bc8<0>(s0)) MV(1,  bc8<1>(s0)) MV(2,  bc8<2>(s0)) MV(3,  bc8<3>(s0)) \
    MV(4,  bc8<4>(s0)) MV(5,  bc8<5>(s0)) MV(6,  bc8<6>(s0)) MV(7,  bc8<7>(s0)) \
    MV(8,  bc8<0>(s1)) MV(9,  bc8<0>(s2)) MV(10, bc8<1>(s1)) MV(11, bc8<1>(s2)) \
    MV(12, bc8<2>(s1)) MV(13, bc8<2>(s2)) MV(14, bc8<3>(s1)) MV(15, bc8<3>(s2)) \
    MV(16, bc8<4>(s1)) MV(17, bc8<4>(s2)) MV(18, bc8<5>(s1)) MV(19, bc8<5>(s2)) \
    MV(20, bc8<6>(s1)) MV(21, bc8<6>(s2)) MV(22, bc8<7>(s1)) MV(23, bc8<7>(s2)) \
} while (0)

__global__ void __launch_bounds__(256, 4)
qcqp_kernel(const float* __restrict__ P, const float* __restrict__ qv,
            float* __restrict__ out, int Btot) {
    const int tid = blockIdx.x * blockDim.x + threadIdx.x;
    const int b = tid >> 3;
    if (b >= Btot) return;
    const int ls = tid & 7;  // lane-in-group; owns cone ls

    const float* __restrict__ Pb = P + (size_t)b * (NN * NN);
    const float* __restrict__ qb = qv + (size_t)b * NN;

    // Own rows of G: {ls, 8+2ls, 9+2ls}  (t of cone ls, x1/x2 of cone ls)
    const int rx = 8 + 2 * ls;

    // ---- Phase 1: G rows (G = P^T P; REG=1e-7 dropped, ~3e-8 rel effect) ,
    //      bb = -(P^T q) own rows ----
    float Gm[3][NN];
    float bb0 = 0.f, bb1 = 0.f, bb2 = 0.f;
#pragma unroll
    for (int il = 0; il < 3; ++il)
#pragma unroll
        for (int j = 0; j < NN; ++j) Gm[il][j] = 0.f;

#pragma unroll 1
    for (int k = 0; k < NN; ++k) {
        const float* rp = Pb + k * NN;
        float row[NN];
#pragma unroll
        for (int m = 0; m < 6; ++m) {
            const float4 v4 = *reinterpret_cast<const float4*>(rp + 4 * m);
            row[4 * m + 0] = v4.x;
            row[4 * m + 1] = v4.y;
            row[4 * m + 2] = v4.z;
            row[4 * m + 3] = v4.w;
        }
        const float  a0 = rp[ls];                                   // A[k][ls]
        const float2 ax = *reinterpret_cast<const float2*>(rp + rx); // A[k][8+2ls..]
        const float  qk = qb[k];
        bb0 = fmaf(-a0,   qk, bb0);
        bb1 = fmaf(-ax.x, qk, bb1);
        bb2 = fmaf(-ax.y, qk, bb2);
#pragma unroll
        for (int j = 0; j < NN; ++j) {
            Gm[0][j] = fmaf(a0,   row[j], Gm[0][j]);
            Gm[1][j] = fmaf(ax.x, row[j], Gm[1][j]);
            Gm[2][j] = fmaf(ax.y, row[j], Gm[2][j]);
        }
    }

    // ---- Phase 2: power iteration -> step = 1/(L + 1e-12) ----
    float vo0 = 0.20412414523193150818f;  // 1/sqrt(24)
    float vo1 = vo0, vo2 = vo0;

#pragma unroll 1
    for (int it = 0; it < POWER_ITERS; ++it) {
        float g0 = 0.f, g1 = 0.f, g2 = 0.f;
        MATVEC(vo0, vo1, vo2);
        float n2 = g0 * g0 + g1 * g1 + g2 * g2;
        n2 += gx1(n2);
        n2 += gx2(n2);
        n2 += gx4(n2);
        const float inv = __builtin_amdgcn_rsqf(fmaxf(n2, 1e-60f));
        vo0 = g0 * inv; vo1 = g1 * inv; vo2 = g2 * inv;
    }
    float step;
    {
        float g0 = 0.f, g1 = 0.f, g2 = 0.f;
        MATVEC(vo0, vo1, vo2);
        float Lp = vo0 * g0 + vo1 * g1 + vo2 * g2;
        Lp += gx1(Lp);
        Lp += gx2(Lp);
        Lp += gx4(Lp);
        step = __builtin_amdgcn_rcpf(Lp + 1e-12f);
    }

    // ---- Phase 3: FISTA ----
    float yo0 = 0.f, yo1 = 0.f, yo2 = 0.f;
    float lo0 = 0.f, lo1 = 0.f, lo2 = 0.f;
    float tk = 1.f;

#pragma unroll 1
    for (int it = 0; it < FISTA_ITERS; ++it) {
        float g0 = bb0, g1 = bb1, g2 = bb2;
        MATVEC(yo0, yo1, yo2);
        const float t  = fmaf(-step, g0, yo0);
        const float x1 = fmaf(-step, g1, yo1);
        const float x2 = fmaf(-step, g2, yo2);
        // SOC projection of (t; x1, x2) — fully lane-local
        const float nx    = __builtin_amdgcn_sqrtf(x1 * x1 + x2 * x2);
        const float alpha = 0.5f * (t + nx);
        const bool inside = (nx <= t);
        const bool zero_  = (nx <= -t);
        const float ln0 = inside ? t : (zero_ ? 0.f : alpha);
        const float sc  = inside ? 1.f
                                 : (zero_ ? 0.f
                                          : alpha * __builtin_amdgcn_rcpf(fmaxf(nx, 1e-12f)));
        const float ln1 = x1 * sc;
        const float ln2 = x2 * sc;
        const float tkn = 0.5f * (1.f + __builtin_amdgcn_sqrtf(fmaf(4.f * tk, tk, 1.f)));
        const float bet = (tk - 1.f) / tkn;  // wave-uniform-ish scalar; cheap either way
        tk = tkn;
        yo0 = fmaf(bet, ln0 - lo0, ln0);
        yo1 = fmaf(bet, ln1 - lo1, ln1);
        yo2 = fmaf(bet, ln2 - lo2, ln2);
        lo0 = ln0; lo1 = ln1; lo2 = ln2;
    }

    // ---- store own components (disjoint across the group, covers all 24) ----
    float* ob = out + (size_t)b * NN;
    ob[ls] = lo0;
    *reinterpret_cast<float2*>(ob + rx) = make_float2(lo1, lo2);
}

extern "C" void kernel_launch(void* const* d_in, const int* in_sizes, int n_in,
                              void* d_out, int out_size, void* d_ws, size_t ws_size,
                              hipStream_t stream) {
    const float* P = (const float*)d_in[0];
    const float* q = (const float*)d_in[1];
    float* out = (float*)d_out;
    const int Btot = in_sizes[0] / (NN * NN);
    const long long threads = 8LL * Btot;
    const int block = 256;
    const int grid = (int)((threads + block - 1) / block);
    qcqp_kernel<<<grid, block, 0, stream>>>(P, q, out, Btot);
}

// Round 4
// 176.241 us; speedup vs baseline: 10.7661x; 1.1187x over previous
//
#include <hip/hip_runtime.h>

#define NN 24
#define POWER_ITERS 30
#define FISTA_ITERS 200

typedef float v2f __attribute__((ext_vector_type(2)));
typedef float v4f __attribute__((ext_vector_type(4)));

__device__ __forceinline__ v2f fma2(v2f a, v2f b, v2f c) {
    return __builtin_elementwise_fma(a, b, c);
}

// 8-lane-group XOR reductions (only used in the power phase)
__device__ __forceinline__ float gx1(float v) {
    return __int_as_float(__builtin_amdgcn_ds_swizzle(__float_as_int(v), 0x041F));
}
__device__ __forceinline__ float gx2(float v) {
    return __int_as_float(__builtin_amdgcn_ds_swizzle(__float_as_int(v), 0x081F));
}
__device__ __forceinline__ float gx4(float v) {
    return __int_as_float(__builtin_amdgcn_ds_swizzle(__float_as_int(v), 0x101F));
}

// Read the group's full 24-vector from LDS and compute the 3 owned dot
// products (rows of G held as float2 pairs), seeded with bias values.
#define MATVEC_LDS(gp, b0_, b1_, b2_, g0_, g1_, g2_) do {                      \
    v2f y2_[12];                                                               \
    _Pragma("unroll")                                                          \
    for (int m_ = 0; m_ < 6; ++m_) {                                           \
        const v4f r_ = *reinterpret_cast<const v4f*>((gp) + 4 * m_);           \
        y2_[2 * m_]     = (v2f){r_.x, r_.y};                                   \
        y2_[2 * m_ + 1] = (v2f){r_.z, r_.w};                                   \
    }                                                                          \
    v2f a0_ = (v2f){(b0_), 0.f}, a1_ = (v2f){(b1_), 0.f}, a2_ = (v2f){(b2_), 0.f}; \
    _Pragma("unroll")                                                          \
    for (int p_ = 0; p_ < 12; ++p_) {                                          \
        a0_ = fma2(G0[p_], y2_[p_], a0_);                                      \
        a1_ = fma2(G1[p_], y2_[p_], a1_);                                      \
        a2_ = fma2(G2[p_], y2_[p_], a2_);                                      \
    }                                                                          \
    g0_ = a0_.x + a0_.y; g1_ = a1_.x + a1_.y; g2_ = a2_.x + a2_.y;             \
} while (0)

__global__ __attribute__((amdgpu_waves_per_eu(4, 4))) void __launch_bounds__(256)
qcqp_kernel(const float* __restrict__ P, const float* __restrict__ qv,
            float* __restrict__ out, int Btot) {
    const int tid = blockIdx.x * blockDim.x + threadIdx.x;
    const int b = tid >> 3;
    if (b >= Btot) return;
    const int ls = tid & 7;       // lane-in-group; owns cone ls
    const int rx = 8 + 2 * ls;    // global rows {ls, rx, rx+1}

    // 32 groups per 256-thread block, 24 floats each (stride 96B -> 2-way
    // bank aliasing only, which is free). Wave-synchronous use: a group is
    // always within one wave, so no __syncthreads needed.
    __shared__ float sy[32 * NN];
    float* gp = &sy[(threadIdx.x >> 3) * NN];

    const float* __restrict__ Pb = P + (size_t)b * (NN * NN);
    const float* __restrict__ qb = qv + (size_t)b * NN;

    // ---- Phase 1: own 3 rows of G = P^T P (REG dropped, ~3e-8 rel effect),
    //      bb = -(P^T q) own rows. G rows stored as 12 float2 pairs. ----
    v2f G0[12], G1[12], G2[12];
#pragma unroll
    for (int p = 0; p < 12; ++p) { G0[p] = (v2f){0.f, 0.f}; G1[p] = (v2f){0.f, 0.f}; G2[p] = (v2f){0.f, 0.f}; }
    float bb0 = 0.f, bb1 = 0.f, bb2 = 0.f;

#pragma unroll 1
    for (int k = 0; k < NN; ++k) {
        const float* rp = Pb + k * NN;
        v2f row2[12];
#pragma unroll
        for (int m = 0; m < 6; ++m) {
            const v4f r = *reinterpret_cast<const v4f*>(rp + 4 * m);
            row2[2 * m]     = (v2f){r.x, r.y};
            row2[2 * m + 1] = (v2f){r.z, r.w};
        }
        const float  a0 = rp[ls];
        const float2 ax = *reinterpret_cast<const float2*>(rp + rx);
        const float  qk = qb[k];
        bb0 = fmaf(-a0,   qk, bb0);
        bb1 = fmaf(-ax.x, qk, bb1);
        bb2 = fmaf(-ax.y, qk, bb2);
        const v2f a0s = (v2f){a0, a0};
        const v2f a1s = (v2f){ax.x, ax.x};
        const v2f a2s = (v2f){ax.y, ax.y};
#pragma unroll
        for (int p = 0; p < 12; ++p) {
            G0[p] = fma2(a0s, row2[p], G0[p]);
            G1[p] = fma2(a1s, row2[p], G1[p]);
            G2[p] = fma2(a2s, row2[p], G2[p]);
        }
    }

    // ---- Phase 2: power iteration -> step = 1/(L + 1e-12) ----
    float vo0 = 0.20412414523193150818f;  // 1/sqrt(24)
    float vo1 = vo0, vo2 = vo0;
    gp[ls] = vo0;
    *reinterpret_cast<v2f*>(gp + rx) = (v2f){vo1, vo2};
    __builtin_amdgcn_wave_barrier();

#pragma unroll 1
    for (int it = 0; it < POWER_ITERS; ++it) {
        float g0, g1, g2;
        MATVEC_LDS(gp, 0.f, 0.f, 0.f, g0, g1, g2);
        float n2 = g0 * g0 + g1 * g1 + g2 * g2;
        n2 += gx1(n2);
        n2 += gx2(n2);
        n2 += gx4(n2);
        const float inv = __builtin_amdgcn_rsqf(fmaxf(n2, 1e-60f));
        vo0 = g0 * inv; vo1 = g1 * inv; vo2 = g2 * inv;
        __builtin_amdgcn_wave_barrier();   // all lanes done reading before overwrite
        gp[ls] = vo0;
        *reinterpret_cast<v2f*>(gp + rx) = (v2f){vo1, vo2};
        __builtin_amdgcn_wave_barrier();
    }
    float step;
    {
        float g0, g1, g2;
        MATVEC_LDS(gp, 0.f, 0.f, 0.f, g0, g1, g2);
        float Lp = vo0 * g0 + vo1 * g1 + vo2 * g2;
        Lp += gx1(Lp);
        Lp += gx2(Lp);
        Lp += gx4(Lp);
        step = __builtin_amdgcn_rcpf(Lp + 1e-12f);
    }

    // ---- Phase 3: FISTA ----
    float yo0 = 0.f, yo1 = 0.f, yo2 = 0.f;
    float lo0 = 0.f, lo1 = 0.f, lo2 = 0.f;
    float tk = 1.f;
    __builtin_amdgcn_wave_barrier();
    gp[ls] = 0.f;
    *reinterpret_cast<v2f*>(gp + rx) = (v2f){0.f, 0.f};
    __builtin_amdgcn_wave_barrier();

#pragma unroll 1
    for (int it = 0; it < FISTA_ITERS; ++it) {
        float g0, g1, g2;
        MATVEC_LDS(gp, bb0, bb1, bb2, g0, g1, g2);
        const float t  = fmaf(-step, g0, yo0);
        const float x1 = fmaf(-step, g1, yo1);
        const float x2 = fmaf(-step, g2, yo2);
        // SOC projection (lane-local: lane owns exactly cone ls)
        const float nx    = __builtin_amdgcn_sqrtf(x1 * x1 + x2 * x2);
        const float alpha = 0.5f * (t + nx);
        const bool inside = (nx <= t);
        const bool zero_  = (nx <= -t);
        const float ln0 = inside ? t : (zero_ ? 0.f : alpha);
        const float sc  = inside ? 1.f
                                 : (zero_ ? 0.f
                                          : alpha * __builtin_amdgcn_rcpf(fmaxf(nx, 1e-12f)));
        const float ln1 = x1 * sc;
        const float ln2 = x2 * sc;
        const float tkn = 0.5f * (1.f + __builtin_amdgcn_sqrtf(fmaf(4.f * tk, tk, 1.f)));
        const float bet = (tk - 1.f) / tkn;
        tk = tkn;
        yo0 = fmaf(bet, ln0 - lo0, ln0);
        yo1 = fmaf(bet, ln1 - lo1, ln1);
        yo2 = fmaf(bet, ln2 - lo2, ln2);
        lo0 = ln0; lo1 = ln1; lo2 = ln2;
        __builtin_amdgcn_wave_barrier();   // all lanes done reading before overwrite
        gp[ls] = yo0;
        *reinterpret_cast<v2f*>(gp + rx) = (v2f){yo1, yo2};
        __builtin_amdgcn_wave_barrier();
    }

    // ---- store own components (disjoint across the group, covers all 24) ----
    float* ob = out + (size_t)b * NN;
    ob[ls] = lo0;
    *reinterpret_cast<v2f*>(ob + rx) = (v2f){lo1, lo2};
}

extern "C" void kernel_launch(void* const* d_in, const int* in_sizes, int n_in,
                              void* d_out, int out_size, void* d_ws, size_t ws_size,
                              hipStream_t stream) {
    const float* P = (const float*)d_in[0];
    const float* q = (const float*)d_in[1];
    float* out = (float*)d_out;
    const int Btot = in_sizes[0] / (NN * NN);
    const long long threads = 8LL * Btot;
    const int block = 256;
    const int grid = (int)((threads + block - 1) / block);
    qcqp_kernel<<<grid, block, 0, stream>>>(P, q, out, Btot);
}